// Round 1
// baseline (1051.502 us; speedup 1.0000x reference)
//
#include <hip/hip_runtime.h>
#include <stdint.h>

static constexpr int NT = 26000;   // n_terms
static constexpr int NE = 120000;  // n_edges

// ---------- bf16 helpers ----------
__device__ __forceinline__ float bf_lo(uint32_t u){ union{uint32_t u; float f;} a; a.u = u<<16; return a.f; }
__device__ __forceinline__ float bf_hi(uint32_t u){ union{uint32_t u; float f;} a; a.u = u & 0xffff0000u; return a.f; }
__device__ __forceinline__ uint32_t f2b(float f){ union{float f; uint32_t u;} a; a.f=f; return (a.u + 0x7fffu + ((a.u>>16)&1u))>>16; }

template<int U>
__device__ __forceinline__ void load_u(uint32_t* d, const uint32_t* __restrict__ p){
  if constexpr (U==4){ uint4 v = *(const uint4*)p; d[0]=v.x; d[1]=v.y; d[2]=v.z; d[3]=v.w; }
  else if constexpr (U==2){ uint2 v = *(const uint2*)p; d[0]=v.x; d[1]=v.y; }
  else {
    #pragma unroll
    for (int u=0;u<U;u++) d[u]=p[u];
  }
}

// ---------- CSR build ----------
__global__ __launch_bounds__(256) void k_zero_deg(int* __restrict__ deg){
  int i = blockIdx.x*256 + threadIdx.x;
  if (i < NT) deg[i] = 0;
}
__global__ __launch_bounds__(256) void k_count(const int* __restrict__ ei, int* __restrict__ deg){
  int e = blockIdx.x*256 + threadIdx.x;
  if (e < NE) atomicAdd(&deg[ei[e]], 1);
}
__global__ __launch_bounds__(1024) void k_scan(const int* __restrict__ deg, int* __restrict__ rp,
                                               int* __restrict__ cur, float* __restrict__ dinv){
  __shared__ int part[1024];
  const int t = threadIdx.x;
  const int CH = (NT + 1023)/1024;   // 26
  const int base = t*CH;
  int sum = 0;
  for (int i=0;i<CH;i++){ int idx=base+i; if (idx<NT) sum += deg[idx]; }
  part[t] = sum;
  __syncthreads();
  for (int off=1; off<1024; off<<=1){
    int v = (t>=off) ? part[t-off] : 0;
    __syncthreads();
    part[t] += v;
    __syncthreads();
  }
  int run = (t==0) ? 0 : part[t-1];
  for (int i=0;i<CH;i++){
    int idx = base+i;
    if (idx<NT){
      int d = deg[idx];
      rp[idx] = run; cur[idx] = run;
      dinv[idx] = 1.0f / (float)(d>1?d:1);
      run += d;
    }
  }
  if (t==1023) rp[NT] = part[1023];
}
__global__ __launch_bounds__(256) void k_fill(const int* __restrict__ ei, int* __restrict__ cur,
                                              int* __restrict__ cols){
  int e = blockIdx.x*256 + threadIdx.x;
  if (e < NE){
    int r = ei[e];
    int pos = atomicAdd(&cur[r], 1);
    cols[pos] = ei[NE + e];
  }
}

// ---------- build h0: [N][32][32] bf16, features = [x(14), emb(8), zeros(10)] ----------
__global__ __launch_bounds__(256) void k_build_h0(const float* __restrict__ x, const int* __restrict__ tidx,
                                                  const float* __restrict__ emb, uint32_t* __restrict__ h0){
  int n = blockIdx.x*8 + (threadIdx.x>>5);
  int b = threadIdx.x & 31;
  const float* xr = x + ((size_t)b*NT + n)*14;
  const float* er = emb + (size_t)tidx[n]*8;
  float v[32];
  #pragma unroll
  for (int i=0;i<14;i++) v[i]=xr[i];
  #pragma unroll
  for (int i=0;i<8;i++) v[14+i]=er[i];
  #pragma unroll
  for (int i=22;i<32;i++) v[i]=0.f;
  uint32_t* dst = h0 + ((size_t)n*32 + b)*16;
  #pragma unroll
  for (int u=0;u<16;u++) dst[u] = f2b(v[2*u]) | (f2b(v[2*u+1])<<16);
}

// ---------- fused layer: s = own + deg_inv * sum(neighbors); h_out = relu(s @ W^T + b) ----------
// BB: batch chunk (32). One block (256 thr) per node.
template<int BB, int CIN, int COUT, bool FINAL>
__global__ __launch_bounds__(256) void k_layer(
    const uint32_t* __restrict__ hin,   // [NT][BB][CIN] bf16 (as uints)
    uint32_t* __restrict__ hout,        // [NT][BB][COUT] bf16 (unused if FINAL)
    const int* __restrict__ rp, const int* __restrict__ cols,
    const float* __restrict__ dinv,
    const float* __restrict__ W, int kreal,      // W[COUT][kreal] row-major
    const float* __restrict__ bias,
    const float* __restrict__ Wo, const float* __restrict__ bo,
    float* __restrict__ out)                     // [64][NT], pre-offset by chunk
{
  constexpr int SP  = CIN + 4;        // s row stride (floats) — keeps float4 rows 16B-aligned, banks spread
  constexpr int WP  = COUT + 4;       // Wt row stride
  constexpr int UPT = BB*CIN/512;     // uints per thread for node-block load (2 or 4)
  constexpr int EPT = 2*UPT;          // bf16 elems per thread
  constexpr int OPT = COUT/16;        // outputs per thread in o (4 or 2)
  constexpr int NBI = BB/16;          // outputs per thread in b (2)

  __shared__ float s[BB*SP];
  __shared__ float Wt[CIN*WP];        // Wt[k][o] = W[o][k] (zero-padded rows k>=kreal)
  __shared__ float bs[COUT];
  __shared__ float wos[FINAL?32:1];
  __shared__ float h3[FINAL?BB*33:1];

  const int r = blockIdx.x;
  const int t = threadIdx.x;

  // load W transposed into LDS
  for (int idx = t; idx < CIN*COUT; idx += 256){
    int k = idx / COUT, o = idx - k*COUT;
    Wt[k*WP + o] = (k < kreal) ? W[o*kreal + k] : 0.f;
  }
  if (t < COUT) bs[t] = bias[t];
  if (FINAL && t < 32) wos[t] = Wo[t];

  // ---- phase A: own + neighbor aggregation (register accumulate, disjoint elements) ----
  const int b  = (t*EPT)/CIN;
  const int k0 = (t*EPT)%CIN;
  const uint32_t* own = hin + (size_t)r*(BB*CIN/2) + (size_t)t*UPT;

  float mine[EPT], acc[EPT];
  uint32_t tmp[UPT];
  load_u<UPT>(tmp, own);
  #pragma unroll
  for (int u=0;u<UPT;u++){ mine[2*u]=bf_lo(tmp[u]); mine[2*u+1]=bf_hi(tmp[u]); }
  #pragma unroll
  for (int j=0;j<EPT;j++) acc[j]=0.f;

  const int e0 = rp[r], e1 = rp[r+1];
  for (int e=e0; e<e1; e++){
    const uint32_t* nb = hin + (size_t)cols[e]*(BB*CIN/2) + (size_t)t*UPT;
    load_u<UPT>(tmp, nb);
    #pragma unroll
    for (int u=0;u<UPT;u++){ acc[2*u]+=bf_lo(tmp[u]); acc[2*u+1]+=bf_hi(tmp[u]); }
  }
  const float di = dinv[r];
  #pragma unroll
  for (int j=0;j<EPT;j++) s[b*SP + k0 + j] = mine[j] + di*acc[j];
  __syncthreads();

  // ---- phase B: [BB,CIN] @ Wt -> [BB,COUT], register-blocked NBI x OPT per thread ----
  const int b0 = (t>>4)*NBI;
  const int o0 = (t&15)*OPT;
  float ao[NBI][OPT];
  #pragma unroll
  for (int i=0;i<NBI;i++)
    #pragma unroll
    for (int j=0;j<OPT;j++) ao[i][j]=0.f;

  #pragma unroll
  for (int kb=0; kb<CIN; kb+=4){
    float4 sv[NBI];
    #pragma unroll
    for (int i=0;i<NBI;i++) sv[i] = *(const float4*)&s[(b0+i)*SP + kb];
    #pragma unroll
    for (int kk=0;kk<4;kk++){
      float wv[OPT];
      if constexpr (OPT==4){
        float4 w = *(const float4*)&Wt[(kb+kk)*WP + o0];
        wv[0]=w.x; wv[1]=w.y; wv[2]=w.z; wv[3]=w.w;
      } else {
        float2 w = *(const float2*)&Wt[(kb+kk)*WP + o0];
        wv[0]=w.x; wv[1]=w.y;
      }
      #pragma unroll
      for (int i=0;i<NBI;i++){
        float sc = (&sv[i].x)[kk];
        #pragma unroll
        for (int j=0;j<OPT;j++) ao[i][j] += sc*wv[j];
      }
    }
  }

  if constexpr (!FINAL){
    #pragma unroll
    for (int i=0;i<NBI;i++){
      uint32_t p[OPT/2];
      #pragma unroll
      for (int j=0;j<OPT;j+=2){
        float v0 = ao[i][j]   + bs[o0+j];   v0 = v0>0.f?v0:0.f;
        float v1 = ao[i][j+1] + bs[o0+j+1]; v1 = v1>0.f?v1:0.f;
        p[j/2] = f2b(v0) | (f2b(v1)<<16);
      }
      uint32_t* dst = hout + (size_t)r*(BB*COUT/2) + (size_t)(b0+i)*(COUT/2) + o0/2;
      if constexpr (OPT==4){ *(uint2*)dst = make_uint2(p[0], p[1]); }
      else { dst[0] = p[0]; }
    }
  } else {
    #pragma unroll
    for (int i=0;i<NBI;i++)
      #pragma unroll
      for (int j=0;j<OPT;j++){
        float v = ao[i][j] + bs[o0+j];
        h3[(b0+i)*33 + o0+j] = v>0.f?v:0.f;
      }
    __syncthreads();
    if (t < BB){
      float z = bo[0];
      #pragma unroll
      for (int o=0;o<32;o++) z += h3[t*33+o]*wos[o];
      out[(size_t)t*NT + r] = 1.f/(1.f+expf(-z));
    }
  }
}

// ---------- workspace layout (bytes) ----------
static constexpr size_t OFF_B    = 106496000;                 // bufB after bufA (26000*32*64*2 each)
static constexpr size_t OFF_DEG  = 212992000;
static constexpr size_t OFF_RP   = OFF_DEG + 104000;
static constexpr size_t OFF_CUR  = OFF_RP  + 104016;
static constexpr size_t OFF_COLS = OFF_CUR + 104000;
static constexpr size_t OFF_DINV = OFF_COLS + 480000;
static constexpr size_t WS_NEED  = OFF_DINV + 104000;         // ~214 MB

extern "C" void kernel_launch(void* const* d_in, const int* in_sizes, int n_in,
                              void* d_out, int out_size, void* d_ws, size_t ws_size,
                              hipStream_t stream)
{
  const float* x    = (const float*)d_in[0];
  const int*   ei   = (const int*)  d_in[1];
  const int*   tidx = (const int*)  d_in[2];
  const float* emb  = (const float*)d_in[3];
  const float* W1   = (const float*)d_in[4];
  const float* b1   = (const float*)d_in[5];
  const float* W2   = (const float*)d_in[6];
  const float* b2   = (const float*)d_in[7];
  const float* W3   = (const float*)d_in[8];
  const float* b3   = (const float*)d_in[9];
  const float* Wo   = (const float*)d_in[10];
  const float* bo   = (const float*)d_in[11];
  float* out = (float*)d_out;

  if (ws_size < WS_NEED) return;  // fail validation cleanly rather than corrupt memory

  char* ws = (char*)d_ws;
  uint32_t* bufA = (uint32_t*)(ws);
  uint32_t* bufB = (uint32_t*)(ws + OFF_B);
  int*   deg  = (int*)  (ws + OFF_DEG);
  int*   rp   = (int*)  (ws + OFF_RP);
  int*   cur  = (int*)  (ws + OFF_CUR);
  int*   cols = (int*)  (ws + OFF_COLS);
  float* dinv = (float*)(ws + OFF_DINV);

  k_zero_deg<<<(NT+255)/256, 256, 0, stream>>>(deg);
  k_count   <<<(NE+255)/256, 256, 0, stream>>>(ei, deg);
  k_scan    <<<1, 1024, 0, stream>>>(deg, rp, cur, dinv);
  k_fill    <<<(NE+255)/256, 256, 0, stream>>>(ei, cur, cols);

  for (int ch = 0; ch < 2; ch++){
    k_build_h0<<<NT/8, 256, 0, stream>>>(x + (size_t)ch*32*NT*14, tidx, emb, bufA);
    k_layer<32,32,64,false><<<NT, 256, 0, stream>>>(bufA, bufB, rp, cols, dinv, W1, 22, b1,
                                                    nullptr, nullptr, nullptr);
    k_layer<32,64,64,false><<<NT, 256, 0, stream>>>(bufB, bufA, rp, cols, dinv, W2, 64, b2,
                                                    nullptr, nullptr, nullptr);
    k_layer<32,64,32,true ><<<NT, 256, 0, stream>>>(bufA, nullptr, rp, cols, dinv, W3, 64, b3,
                                                    Wo, bo, out + (size_t)ch*32*NT);
  }
}

// Round 2
// 720.046 us; speedup vs baseline: 1.4603x; 1.4603x over previous
//
#include <hip/hip_runtime.h>
#include <stdint.h>

static constexpr int NT = 26000;   // n_terms
static constexpr int NE = 120000;  // n_edges

typedef __attribute__((ext_vector_type(8))) short short8;   // 8 bf16 = 4 VGPR (MFMA A/B frag)
typedef __attribute__((ext_vector_type(4))) float f32x4;    // MFMA C/D frag

// ---------- bf16 helpers ----------
__device__ __forceinline__ float bf_lo(uint32_t u){ union{uint32_t u; float f;} a; a.u = u<<16; return a.f; }
__device__ __forceinline__ float bf_hi(uint32_t u){ union{uint32_t u; float f;} a; a.u = u & 0xffff0000u; return a.f; }
__device__ __forceinline__ uint32_t f2b(float f){ union{float f; uint32_t u;} a; a.f=f; return (a.u + 0x7fffu + ((a.u>>16)&1u))>>16; }

// ---------- CSR build ----------
__global__ __launch_bounds__(256) void k_zero_deg(int* __restrict__ deg){
  int i = blockIdx.x*256 + threadIdx.x;
  if (i < NT) deg[i] = 0;
}
__global__ __launch_bounds__(256) void k_count(const int* __restrict__ ei, int* __restrict__ deg){
  int e = blockIdx.x*256 + threadIdx.x;
  if (e < NE) atomicAdd(&deg[ei[e]], 1);
}
__global__ __launch_bounds__(1024) void k_scan(const int* __restrict__ deg, int* __restrict__ rp,
                                               int* __restrict__ cur, float* __restrict__ dinv){
  __shared__ int part[1024];
  const int t = threadIdx.x;
  const int CH = (NT + 1023)/1024;
  const int base = t*CH;
  int sum = 0;
  for (int i=0;i<CH;i++){ int idx=base+i; if (idx<NT) sum += deg[idx]; }
  part[t] = sum;
  __syncthreads();
  for (int off=1; off<1024; off<<=1){
    int v = (t>=off) ? part[t-off] : 0;
    __syncthreads();
    part[t] += v;
    __syncthreads();
  }
  int run = (t==0) ? 0 : part[t-1];
  for (int i=0;i<CH;i++){
    int idx = base+i;
    if (idx<NT){
      int d = deg[idx];
      rp[idx] = run; cur[idx] = run;
      dinv[idx] = 1.0f / (float)(d>1?d:1);
      run += d;
    }
  }
  if (t==1023) rp[NT] = part[1023];
}
__global__ __launch_bounds__(256) void k_fill(const int* __restrict__ ei, int* __restrict__ cur,
                                              int* __restrict__ cols){
  int e = blockIdx.x*256 + threadIdx.x;
  if (e < NE){
    int r = ei[e];
    int pos = atomicAdd(&cur[r], 1);
    cols[pos] = ei[NE + e];
  }
}

// ---------- build h0: [N][32][32] bf16, features = [x(14), emb(8), zeros(10)] ----------
__global__ __launch_bounds__(256) void k_build_h0(const float* __restrict__ x, const int* __restrict__ tidx,
                                                  const float* __restrict__ emb, uint32_t* __restrict__ h0){
  int n = blockIdx.x*8 + (threadIdx.x>>5);
  int b = threadIdx.x & 31;
  const float* xr = x + ((size_t)b*NT + n)*14;
  const float* er = emb + (size_t)tidx[n]*8;
  float v[32];
  #pragma unroll
  for (int i=0;i<14;i++) v[i]=xr[i];
  #pragma unroll
  for (int i=0;i<8;i++) v[14+i]=er[i];
  #pragma unroll
  for (int i=22;i<32;i++) v[i]=0.f;
  uint32_t* dst = h0 + ((size_t)n*32 + b)*16;
  #pragma unroll
  for (int u=0;u<16;u++) dst[u] = f2b(v[2*u]) | (f2b(v[2*u+1])<<16);
}

// ---------- fused layer (MFMA): per wave, 2 nodes; aggregate into B-frags in regs;
// D = W * s^T via mfma_f32_16x16x32_bf16. A = W[o][k] (k-consec), B = s[r][k] (k-consec).
// D layout: col(lane&15) = r, row((lane>>4)*4+reg) = o -> 4 consecutive o per lane.
template<int CIN, int COUT, bool FINAL>
__global__ __launch_bounds__(256,4) void k_layer(
    const uint32_t* __restrict__ hin,   // [NT][32][CIN] bf16 (u32 pairs)
    uint32_t* __restrict__ hout,        // [NT][32][COUT] bf16 (unused if FINAL)
    const int* __restrict__ rp, const int* __restrict__ cols,
    const float* __restrict__ dinv,
    const float* __restrict__ W, int kreal,      // W[COUT][kreal] row-major f32
    const float* __restrict__ bias,
    const float* __restrict__ Wo, const float* __restrict__ bo,
    float* __restrict__ out)                     // [32][NT] f32, pre-offset by chunk
{
  constexpr int KS  = CIN/32;          // mfma k-steps (1 or 2)
  constexpr int OT  = COUT/16;         // o tiles (4 or 2)
  constexpr int WP  = CIN + 8;         // Wt row stride (bf16) -> 2-way banked frag reads
  constexpr int NBU = 32*CIN/2;        // u32 per node block

  __shared__ uint16_t Wt[COUT*WP];
  __shared__ float bsh[COUT];
  __shared__ float wsh[FINAL?32:4];

  const int t = threadIdx.x;
  // stage W -> LDS as bf16, zero-pad k >= kreal
  for (int idx = t; idx < COUT*CIN; idx += 256){
    int o = idx / CIN, k = idx - o*CIN;
    float v = (k < kreal) ? W[o*kreal + k] : 0.f;
    Wt[o*WP + k] = (uint16_t)f2b(v);
  }
  if (t < COUT) bsh[t] = bias[t];
  if (FINAL && t < 32) wsh[t] = Wo[t];
  __syncthreads();

  const int lane = t & 63;
  const int w    = t >> 6;
  const int l15  = lane & 15;
  const int lg   = lane >> 4;

  // A-frags (W) once per wave, reused for both nodes
  short8 afrag[OT][KS];
  #pragma unroll
  for (int ot=0; ot<OT; ot++)
    #pragma unroll
    for (int ks=0; ks<KS; ks++)
      afrag[ot][ks] = *reinterpret_cast<const short8*>(&Wt[(ot*16 + l15)*WP + lg*8 + ks*32]);

  #pragma unroll 1
  for (int nn=0; nn<2; nn++){
    const int node = blockIdx.x*8 + w*2 + nn;
    const int e0 = __builtin_amdgcn_readfirstlane(rp[node]);
    const int e1 = __builtin_amdgcn_readfirstlane(rp[node+1]);
    const float di = dinv[node];

    // lane seg (rt,ks): brow = rt*16+l15, k0 = lg*8+ks*32 ; u32 off = brow*CIN/2 + lg*4 + ks*16
    float acc[2][KS][8];
    #pragma unroll
    for (int rt=0;rt<2;rt++)
      #pragma unroll
      for (int ks=0;ks<KS;ks++)
        #pragma unroll
        for (int j=0;j<8;j++) acc[rt][ks][j]=0.f;

    for (int e=e0; e<e1; e++){
      const int c = __builtin_amdgcn_readfirstlane(cols[e]);
      const uint32_t* nb = hin + (size_t)c*NBU;
      #pragma unroll
      for (int rt=0;rt<2;rt++)
        #pragma unroll
        for (int ks=0;ks<KS;ks++){
          uint4 v = *reinterpret_cast<const uint4*>(nb + ((rt*16+l15)*(CIN/2) + lg*4 + ks*16));
          acc[rt][ks][0]+=bf_lo(v.x); acc[rt][ks][1]+=bf_hi(v.x);
          acc[rt][ks][2]+=bf_lo(v.y); acc[rt][ks][3]+=bf_hi(v.y);
          acc[rt][ks][4]+=bf_lo(v.z); acc[rt][ks][5]+=bf_hi(v.z);
          acc[rt][ks][6]+=bf_lo(v.w); acc[rt][ks][7]+=bf_hi(v.w);
        }
    }

    // own + di*acc -> bf16 B-frags
    const uint32_t* own = hin + (size_t)node*NBU;
    short8 bfrag[2][KS];
    #pragma unroll
    for (int rt=0;rt<2;rt++)
      #pragma unroll
      for (int ks=0;ks<KS;ks++){
        uint4 v = *reinterpret_cast<const uint4*>(own + ((rt*16+l15)*(CIN/2) + lg*4 + ks*16));
        float s0=bf_lo(v.x)+di*acc[rt][ks][0], s1=bf_hi(v.x)+di*acc[rt][ks][1];
        float s2=bf_lo(v.y)+di*acc[rt][ks][2], s3=bf_hi(v.y)+di*acc[rt][ks][3];
        float s4=bf_lo(v.z)+di*acc[rt][ks][4], s5=bf_hi(v.z)+di*acc[rt][ks][5];
        float s6=bf_lo(v.w)+di*acc[rt][ks][6], s7=bf_hi(v.w)+di*acc[rt][ks][7];
        short8 bf;
        bf[0]=(short)f2b(s0); bf[1]=(short)f2b(s1); bf[2]=(short)f2b(s2); bf[3]=(short)f2b(s3);
        bf[4]=(short)f2b(s4); bf[5]=(short)f2b(s5); bf[6]=(short)f2b(s6); bf[7]=(short)f2b(s7);
        bfrag[rt][ks]=bf;
      }

    // GEMM: D[o][r] for this node's 32 rows
    f32x4 accD[OT][2];
    #pragma unroll
    for (int ot=0;ot<OT;ot++)
      #pragma unroll
      for (int rt=0;rt<2;rt++)
        accD[ot][rt] = f32x4{0.f,0.f,0.f,0.f};
    #pragma unroll
    for (int ks=0;ks<KS;ks++)
      #pragma unroll
      for (int ot=0;ot<OT;ot++)
        #pragma unroll
        for (int rt=0;rt<2;rt++)
          accD[ot][rt] = __builtin_amdgcn_mfma_f32_16x16x32_bf16(afrag[ot][ks], bfrag[rt][ks], accD[ot][rt], 0,0,0);

    if constexpr (!FINAL){
      #pragma unroll
      for (int ot=0;ot<OT;ot++){
        f32x4 bv = *reinterpret_cast<const f32x4*>(&bsh[ot*16 + lg*4]);
        #pragma unroll
        for (int rt=0;rt<2;rt++){
          int brow = rt*16 + l15;
          float v0=fmaxf(accD[ot][rt][0]+bv[0],0.f), v1=fmaxf(accD[ot][rt][1]+bv[1],0.f);
          float v2=fmaxf(accD[ot][rt][2]+bv[2],0.f), v3=fmaxf(accD[ot][rt][3]+bv[3],0.f);
          uint2 p; p.x = f2b(v0) | (f2b(v1)<<16); p.y = f2b(v2) | (f2b(v3)<<16);
          *reinterpret_cast<uint2*>(hout + ((size_t)node*32 + brow)*(COUT/2) + (ot*16 + lg*4)/2) = p;
        }
      }
    } else {
      // head: z[r] = sum_o relu(D+b)*Wo[o]; lane holds o = ot*16+lg*4+j at fixed r
      float z[2] = {0.f, 0.f};
      #pragma unroll
      for (int ot=0;ot<OT;ot++){
        f32x4 bv = *reinterpret_cast<const f32x4*>(&bsh[ot*16 + lg*4]);
        f32x4 wv = *reinterpret_cast<const f32x4*>(&wsh[ot*16 + lg*4]);
        #pragma unroll
        for (int rt=0;rt<2;rt++)
          #pragma unroll
          for (int j=0;j<4;j++){
            float h = fmaxf(accD[ot][rt][j]+bv[j], 0.f);
            z[rt] += h*wv[j];
          }
      }
      const float bo0 = bo[0];
      #pragma unroll
      for (int rt=0;rt<2;rt++){
        float zz = z[rt];
        zz += __shfl_xor(zz, 16, 64);
        zz += __shfl_xor(zz, 32, 64);
        if (lg==0){
          float sg = 1.f/(1.f + expf(-(zz + bo0)));
          out[(size_t)(rt*16 + l15)*NT + node] = sg;
        }
      }
    }
  }
}

// ---------- workspace layout (bytes) ----------
static constexpr size_t OFF_B    = 106496000;                 // bufB after bufA (26000*32*64*2 each)
static constexpr size_t OFF_DEG  = 212992000;
static constexpr size_t OFF_RP   = OFF_DEG + 104000;
static constexpr size_t OFF_CUR  = OFF_RP  + 104016;
static constexpr size_t OFF_COLS = OFF_CUR + 104000;
static constexpr size_t OFF_DINV = OFF_COLS + 480000;
static constexpr size_t WS_NEED  = OFF_DINV + 104000;         // ~214 MB

extern "C" void kernel_launch(void* const* d_in, const int* in_sizes, int n_in,
                              void* d_out, int out_size, void* d_ws, size_t ws_size,
                              hipStream_t stream)
{
  const float* x    = (const float*)d_in[0];
  const int*   ei   = (const int*)  d_in[1];
  const int*   tidx = (const int*)  d_in[2];
  const float* emb  = (const float*)d_in[3];
  const float* W1   = (const float*)d_in[4];
  const float* b1   = (const float*)d_in[5];
  const float* W2   = (const float*)d_in[6];
  const float* b2   = (const float*)d_in[7];
  const float* W3   = (const float*)d_in[8];
  const float* b3   = (const float*)d_in[9];
  const float* Wo   = (const float*)d_in[10];
  const float* bo   = (const float*)d_in[11];
  float* out = (float*)d_out;

  if (ws_size < WS_NEED) return;

  char* ws = (char*)d_ws;
  uint32_t* bufA = (uint32_t*)(ws);
  uint32_t* bufB = (uint32_t*)(ws + OFF_B);
  int*   deg  = (int*)  (ws + OFF_DEG);
  int*   rp   = (int*)  (ws + OFF_RP);
  int*   cur  = (int*)  (ws + OFF_CUR);
  int*   cols = (int*)  (ws + OFF_COLS);
  float* dinv = (float*)(ws + OFF_DINV);

  k_zero_deg<<<(NT+255)/256, 256, 0, stream>>>(deg);
  k_count   <<<(NE+255)/256, 256, 0, stream>>>(ei, deg);
  k_scan    <<<1, 1024, 0, stream>>>(deg, rp, cur, dinv);
  k_fill    <<<(NE+255)/256, 256, 0, stream>>>(ei, cur, cols);

  for (int ch = 0; ch < 2; ch++){
    k_build_h0<<<NT/8, 256, 0, stream>>>(x + (size_t)ch*32*NT*14, tidx, emb, bufA);
    k_layer<32,64,false><<<NT/8, 256, 0, stream>>>(bufA, bufB, rp, cols, dinv, W1, 22, b1,
                                                   nullptr, nullptr, nullptr);
    k_layer<64,64,false><<<NT/8, 256, 0, stream>>>(bufB, bufA, rp, cols, dinv, W2, 64, b2,
                                                   nullptr, nullptr, nullptr);
    k_layer<64,32,true ><<<NT/8, 256, 0, stream>>>(bufA, nullptr, rp, cols, dinv, W3, 64, b3,
                                                   Wo, bo, out + (size_t)ch*32*NT);
  }
}

// Round 4
// 642.095 us; speedup vs baseline: 1.6376x; 1.1214x over previous
//
#include <hip/hip_runtime.h>
#include <stdint.h>

static constexpr int NT = 26000;   // n_terms
static constexpr int NE = 120000;  // n_edges

typedef __attribute__((ext_vector_type(8))) short short8;   // 8 bf16 = 4 VGPR (MFMA A/B frag)
typedef __attribute__((ext_vector_type(4))) float f32x4;    // MFMA C/D frag

// ---------- bf16 helpers ----------
__device__ __forceinline__ float bf_lo(uint32_t u){ union{uint32_t u; float f;} a; a.u = u<<16; return a.f; }
__device__ __forceinline__ float bf_hi(uint32_t u){ union{uint32_t u; float f;} a; a.u = u & 0xffff0000u; return a.f; }
__device__ __forceinline__ uint32_t f2b(float f){ union{float f; uint32_t u;} a; a.f=f; return (a.u + 0x7fffu + ((a.u>>16)&1u))>>16; }

// ---------- CSR build ----------
__global__ __launch_bounds__(256) void k_zero_deg(int* __restrict__ deg){
  int i = blockIdx.x*256 + threadIdx.x;
  if (i < NT) deg[i] = 0;
}
__global__ __launch_bounds__(256) void k_count(const int* __restrict__ ei, int* __restrict__ deg){
  int e = blockIdx.x*256 + threadIdx.x;
  if (e < NE) atomicAdd(&deg[ei[e]], 1);
}
__global__ __launch_bounds__(1024) void k_scan(const int* __restrict__ deg, int* __restrict__ rp,
                                               int* __restrict__ cur){
  __shared__ int part[1024];
  const int t = threadIdx.x;
  const int CH = (NT + 1023)/1024;
  const int base = t*CH;
  int sum = 0;
  for (int i=0;i<CH;i++){ int idx=base+i; if (idx<NT) sum += deg[idx]; }
  part[t] = sum;
  __syncthreads();
  for (int off=1; off<1024; off<<=1){
    int v = (t>=off) ? part[t-off] : 0;
    __syncthreads();
    part[t] += v;
    __syncthreads();
  }
  int run = (t==0) ? 0 : part[t-1];
  for (int i=0;i<CH;i++){
    int idx = base+i;
    if (idx<NT){
      int d = deg[idx];
      rp[idx] = run; cur[idx] = run;
      run += d;
    }
  }
  if (t==1023) rp[NT] = part[1023];
}
__global__ __launch_bounds__(256) void k_fill(const int* __restrict__ ei, int* __restrict__ cur,
                                              int* __restrict__ cols){
  int e = blockIdx.x*256 + threadIdx.x;
  if (e < NE){
    int r = ei[e];
    int pos = atomicAdd(&cur[r], 1);
    cols[pos] = ei[NE + e];
  }
}

// ---------- build h0: [N][32][32] bf16, features = [x(14), emb(8), zeros(10)] ----------
__global__ __launch_bounds__(256) void k_build_h0(const float* __restrict__ x, const int* __restrict__ tidx,
                                                  const float* __restrict__ emb, uint32_t* __restrict__ h0){
  int n = blockIdx.x*8 + (threadIdx.x>>5);
  int b = threadIdx.x & 31;
  const float* xr = x + ((size_t)b*NT + n)*14;
  const float* er = emb + (size_t)tidx[n]*8;
  float v[32];
  #pragma unroll
  for (int i=0;i<14;i++) v[i]=xr[i];
  #pragma unroll
  for (int i=0;i<8;i++) v[14+i]=er[i];
  #pragma unroll
  for (int i=22;i<32;i++) v[i]=0.f;
  uint32_t* dst = h0 + ((size_t)n*32 + b)*16;
  #pragma unroll
  for (int u=0;u<16;u++) dst[u] = f2b(v[2*u]) | (f2b(v[2*u+1])<<16);
}

// ---------- gather helpers ----------
// node block stride = 32 rows * (CIN/2) u32 = 16*CIN u32.  (Round-3 bug: 32*CIN — 2x OOB.)
template<int CIN>
__device__ __forceinline__ void gload(uint4 (&v)[2][CIN/32], const uint32_t* __restrict__ hin,
                                      int c, const uint32_t (&off)[2][CIN/32]){
  const uint32_t* p = hin + (size_t)c * (uint32_t)(16*CIN);
  #pragma unroll
  for (int rt=0;rt<2;rt++)
    #pragma unroll
    for (int ks=0;ks<CIN/32;ks++)
      v[rt][ks] = *reinterpret_cast<const uint4*>(p + off[rt][ks]);
}
template<int KS>
__device__ __forceinline__ void accum(float (&acc)[2][KS][8], const uint4 (&v)[2][KS]){
  #pragma unroll
  for (int rt=0;rt<2;rt++)
    #pragma unroll
    for (int ks=0;ks<KS;ks++){
      acc[rt][ks][0]+=bf_lo(v[rt][ks].x); acc[rt][ks][1]+=bf_hi(v[rt][ks].x);
      acc[rt][ks][2]+=bf_lo(v[rt][ks].y); acc[rt][ks][3]+=bf_hi(v[rt][ks].y);
      acc[rt][ks][4]+=bf_lo(v[rt][ks].z); acc[rt][ks][5]+=bf_hi(v[rt][ks].z);
      acc[rt][ks][6]+=bf_lo(v[rt][ks].w); acc[rt][ks][7]+=bf_hi(v[rt][ks].w);
    }
}

// ---------- fused layer (MFMA): one node per wave; depth-2 edge pipeline;
// D = W * s^T via mfma_f32_16x16x32_bf16. A = W[o][k], B = s[r][k] (k-consec).
// D layout: col(lane&15) = batch row r, row((lane>>4)*4+reg) = out channel o.
template<int CIN, int COUT, bool FINAL>
__global__ __launch_bounds__(256, (CIN==32)?6:4) void k_layer(
    const uint32_t* __restrict__ hin,   // [NT][32][CIN] bf16 (u32 pairs)
    uint32_t* __restrict__ hout,        // [NT][32][COUT] bf16 (unused if FINAL)
    const int* __restrict__ rp, const int* __restrict__ cols,
    const float* __restrict__ W, int kreal,      // W[COUT][kreal] row-major f32
    const float* __restrict__ bias,
    const float* __restrict__ Wo, const float* __restrict__ bo,
    float* __restrict__ out)                     // [32][NT] f32, pre-offset by chunk
{
  constexpr int KS  = CIN/32;          // mfma k-steps (1 or 2)
  constexpr int OT  = COUT/16;         // o tiles (4 or 2)
  constexpr int WP  = CIN + 8;         // Wt row stride (bf16)

  __shared__ uint16_t Wt[COUT*WP];
  __shared__ float bsh[COUT];
  __shared__ float wsh[FINAL?32:4];

  const int t    = threadIdx.x;
  const int lane = t & 63;
  const int w    = t >> 6;
  const int l15  = lane & 15;
  const int lg   = lane >> 4;
  const int node = blockIdx.x*4 + w;

  // per-lane segment offsets (u32 units)
  uint32_t off[2][KS];
  #pragma unroll
  for (int rt=0;rt<2;rt++)
    #pragma unroll
    for (int ks=0;ks<KS;ks++)
      off[rt][ks] = (uint32_t)((rt*16 + l15)*(CIN/2) + lg*4 + ks*16);

  // ---- early scalar + own-block loads (drain at the staging barrier) ----
  const int e0 = __builtin_amdgcn_readfirstlane(rp[node]);
  const int e1 = __builtin_amdgcn_readfirstlane(rp[node+1]);
  int cA = (e0   < e1) ? cols[e0]   : node;
  int cB = (e0+1 < e1) ? cols[e0+1] : node;
  uint4 own[2][KS];
  gload<CIN>(own, hin, node, off);

  // ---- stage W -> LDS as bf16 (zero-pad k >= kreal) ----
  for (int idx = t; idx < COUT*CIN; idx += 256){
    int o = idx / CIN, k = idx - o*CIN;
    float v = (k < kreal) ? W[o*kreal + k] : 0.f;
    Wt[o*WP + k] = (uint16_t)f2b(v);
  }
  if (t < COUT) bsh[t] = bias[t];
  if (FINAL && t < 32) wsh[t] = Wo[t];
  __syncthreads();

  // ---- aggregation: acc = own*deg + sum(neighbors); s = acc/deg ----
  const float degf = (e1 > e0) ? (float)(e1 - e0) : 1.0f;
  const float di   = 1.0f / degf;

  uint4 va[2][KS], vb[2][KS];
  gload<CIN>(va, hin, cA, off);
  gload<CIN>(vb, hin, cB, off);

  float acc[2][KS][8];
  #pragma unroll
  for (int rt=0;rt<2;rt++)
    #pragma unroll
    for (int ks=0;ks<KS;ks++){
      acc[rt][ks][0]=bf_lo(own[rt][ks].x)*degf; acc[rt][ks][1]=bf_hi(own[rt][ks].x)*degf;
      acc[rt][ks][2]=bf_lo(own[rt][ks].y)*degf; acc[rt][ks][3]=bf_hi(own[rt][ks].y)*degf;
      acc[rt][ks][4]=bf_lo(own[rt][ks].z)*degf; acc[rt][ks][5]=bf_hi(own[rt][ks].z)*degf;
      acc[rt][ks][6]=bf_lo(own[rt][ks].w)*degf; acc[rt][ks][7]=bf_hi(own[rt][ks].w)*degf;
    }

  for (int e = e0; e < e1; e += 2){
    int nA = (e+2 < e1) ? cols[e+2] : -1;
    int nB = (e+3 < e1) ? cols[e+3] : -1;
    accum<KS>(acc, va);
    if (nA >= 0) gload<CIN>(va, hin, nA, off);
    if (e+1 < e1) accum<KS>(acc, vb);
    if (nB >= 0) gload<CIN>(vb, hin, nB, off);
  }

  // pack s -> bf16 B-frags
  short8 bfrag[2][KS];
  #pragma unroll
  for (int rt=0;rt<2;rt++)
    #pragma unroll
    for (int ks=0;ks<KS;ks++){
      short8 bf;
      #pragma unroll
      for (int j=0;j<8;j++) bf[j] = (short)f2b(acc[rt][ks][j]*di);
      bfrag[rt][ks]=bf;
    }

  // A-frags from LDS (after loop: not live across it)
  short8 afrag[OT][KS];
  #pragma unroll
  for (int ot=0; ot<OT; ot++)
    #pragma unroll
    for (int ks=0; ks<KS; ks++)
      afrag[ot][ks] = *reinterpret_cast<const short8*>(&Wt[(ot*16 + l15)*WP + lg*8 + ks*32]);

  // GEMM with bias folded into C-init
  f32x4 accD[OT][2];
  #pragma unroll
  for (int ot=0;ot<OT;ot++){
    f32x4 bv = *reinterpret_cast<const f32x4*>(&bsh[ot*16 + lg*4]);
    accD[ot][0] = bv; accD[ot][1] = bv;
  }
  #pragma unroll
  for (int ks=0;ks<KS;ks++)
    #pragma unroll
    for (int ot=0;ot<OT;ot++)
      #pragma unroll
      for (int rt=0;rt<2;rt++)
        accD[ot][rt] = __builtin_amdgcn_mfma_f32_16x16x32_bf16(afrag[ot][ks], bfrag[rt][ks], accD[ot][rt], 0,0,0);

  if constexpr (!FINAL){
    #pragma unroll
    for (int ot=0;ot<OT;ot++)
      #pragma unroll
      for (int rt=0;rt<2;rt++){
        int brow = rt*16 + l15;
        float v0=fmaxf(accD[ot][rt][0],0.f), v1=fmaxf(accD[ot][rt][1],0.f);
        float v2=fmaxf(accD[ot][rt][2],0.f), v3=fmaxf(accD[ot][rt][3],0.f);
        uint2 p; p.x = f2b(v0) | (f2b(v1)<<16); p.y = f2b(v2) | (f2b(v3)<<16);
        *reinterpret_cast<uint2*>(hout + ((size_t)node*32 + brow)*(COUT/2) + (ot*16 + lg*4)/2) = p;
      }
  } else {
    float z[2] = {0.f, 0.f};
    #pragma unroll
    for (int ot=0;ot<OT;ot++){
      f32x4 wv = *reinterpret_cast<const f32x4*>(&wsh[ot*16 + lg*4]);
      #pragma unroll
      for (int rt=0;rt<2;rt++)
        #pragma unroll
        for (int j=0;j<4;j++){
          float h = fmaxf(accD[ot][rt][j], 0.f);
          z[rt] += h*wv[j];
        }
    }
    const float bo0 = bo[0];
    #pragma unroll
    for (int rt=0;rt<2;rt++){
      float zz = z[rt];
      zz += __shfl_xor(zz, 16, 64);
      zz += __shfl_xor(zz, 32, 64);
      if (lg==0){
        float sg = 1.f/(1.f + expf(-(zz + bo0)));
        out[(size_t)(rt*16 + l15)*NT + node] = sg;
      }
    }
  }
}

// ---------- workspace layout (bytes) ----------
static constexpr size_t OFF_B    = 106496000;                 // bufB after bufA (26000*32*64*2 each)
static constexpr size_t OFF_DEG  = 212992000;
static constexpr size_t OFF_RP   = OFF_DEG + 104000;
static constexpr size_t OFF_CUR  = OFF_RP  + 104016;
static constexpr size_t OFF_COLS = OFF_CUR + 104000;
static constexpr size_t WS_NEED  = OFF_COLS + 480000;         // ~214 MB

extern "C" void kernel_launch(void* const* d_in, const int* in_sizes, int n_in,
                              void* d_out, int out_size, void* d_ws, size_t ws_size,
                              hipStream_t stream)
{
  const float* x    = (const float*)d_in[0];
  const int*   ei   = (const int*)  d_in[1];
  const int*   tidx = (const int*)  d_in[2];
  const float* emb  = (const float*)d_in[3];
  const float* W1   = (const float*)d_in[4];
  const float* b1   = (const float*)d_in[5];
  const float* W2   = (const float*)d_in[6];
  const float* b2   = (const float*)d_in[7];
  const float* W3   = (const float*)d_in[8];
  const float* b3   = (const float*)d_in[9];
  const float* Wo   = (const float*)d_in[10];
  const float* bo   = (const float*)d_in[11];
  float* out = (float*)d_out;

  if (ws_size < WS_NEED) return;

  char* ws = (char*)d_ws;
  uint32_t* bufA = (uint32_t*)(ws);
  uint32_t* bufB = (uint32_t*)(ws + OFF_B);
  int*   deg  = (int*)  (ws + OFF_DEG);
  int*   rp   = (int*)  (ws + OFF_RP);
  int*   cur  = (int*)  (ws + OFF_CUR);
  int*   cols = (int*)  (ws + OFF_COLS);

  k_zero_deg<<<(NT+255)/256, 256, 0, stream>>>(deg);
  k_count   <<<(NE+255)/256, 256, 0, stream>>>(ei, deg);
  k_scan    <<<1, 1024, 0, stream>>>(deg, rp, cur);
  k_fill    <<<(NE+255)/256, 256, 0, stream>>>(ei, cur, cols);

  for (int ch = 0; ch < 2; ch++){
    k_build_h0<<<NT/8, 256, 0, stream>>>(x + (size_t)ch*32*NT*14, tidx, emb, bufA);
    k_layer<32,64,false><<<NT/4, 256, 0, stream>>>(bufA, bufB, rp, cols, W1, 22, b1,
                                                   nullptr, nullptr, nullptr);
    k_layer<64,64,false><<<NT/4, 256, 0, stream>>>(bufB, bufA, rp, cols, W2, 64, b2,
                                                   nullptr, nullptr, nullptr);
    k_layer<64,32,true ><<<NT/4, 256, 0, stream>>>(bufA, nullptr, rp, cols, W3, 64, b3,
                                                   Wo, bo, out + (size_t)ch*32*NT);
  }
}